// Round 4
// baseline (438.262 us; speedup 1.0000x reference)
//
#include <hip/hip_runtime.h>
#include <hip/hip_bf16.h>
#include <stdint.h>

#define NROW 8192
#define INF  512
#define OUTF 256

typedef __attribute__((ext_vector_type(8))) short bf16x8;
typedef __attribute__((ext_vector_type(4))) float f32x4;

__device__ __forceinline__ unsigned short f2bf(float x) {
  union { float f; unsigned u; } v; v.f = x;
  unsigned r = v.u + 0x7fffu + ((v.u >> 16) & 1u);   // RNE
  return (unsigned short)(r >> 16);
}
__device__ __forceinline__ unsigned short f2bf_fast(float x) {
  union { float f; unsigned u; } v; v.f = x;
  return (unsigned short)((v.u + 0x8000u) >> 16);    // round-half-up
}
__device__ __forceinline__ float bf2f(unsigned short h) {
  union { unsigned u; float f; } v; v.u = ((unsigned)h) << 16;
  return v.f;
}

__device__ __forceinline__ void async_cp16(const void* g, void* l) {
  __builtin_amdgcn_global_load_lds((const __attribute__((address_space(1))) void*)g,
                                   (__attribute__((address_space(3))) void*)l,
                                   16, 0, 0);
}

// ---- k1: rowsum + A->bf16 convert + W->WsT convert, one kernel ----
// A reads NON-TEMPORAL so the freshly written Abf (134 MB) stays L3-resident
// for k4's re-read (proven −22us in r3). Blocks 0..511 also convert one W
// element each (replaces the separate k_convert_w dispatch).
__global__ __launch_bounds__(256) void k_rowsum_cvt_w(
    const float* __restrict__ A, const float* __restrict__ W,
    float* __restrict__ dv, unsigned short* __restrict__ Abf,
    unsigned short* __restrict__ WsT) {
  if (blockIdx.x < 512) {
    int idx = blockIdx.x * 256 + threadIdx.x;   // 512*256 == 512*256 W elems
    int k = idx >> 8, f = idx & 255;
    WsT[(size_t)f * INF + k] = f2bf(W[idx]);
  }
  int w = threadIdx.x >> 6, lane = threadIdx.x & 63;
  int row = blockIdx.x * 4 + w;
  const f32x4* ar = (const f32x4*)(A + (size_t)row * NROW);
  ushort4* br = (ushort4*)(Abf + (size_t)row * NROW);
  float s = 0.f;
  #pragma unroll 4
  for (int it = 0; it < NROW / 256; ++it) {
    f32x4 v = __builtin_nontemporal_load(&ar[it * 64 + lane]);
    s += (v.x + v.y) + (v.z + v.w);
    ushort4 b;
    b.x = f2bf(v.x); b.y = f2bf(v.y); b.z = f2bf(v.z); b.w = f2bf(v.w);
    br[it * 64 + lane] = b;                // normal store: keep Abf in L3
  }
  #pragma unroll
  for (int off = 32; off > 0; off >>= 1) s += __shfl_down(s, off, 64);
  if (lane == 0) dv[row] = rsqrtf(1.f + s);
}

// ---- k1b: plain rowsum (mid-fallback path) ----
__global__ __launch_bounds__(256) void k_rowsum(
    const float* __restrict__ A, float* __restrict__ dv) {
  int w = threadIdx.x >> 6, lane = threadIdx.x & 63;
  int row = blockIdx.x * 4 + w;
  const f32x4* ar = (const f32x4*)(A + (size_t)row * NROW);
  float s = 0.f;
  #pragma unroll 4
  for (int it = 0; it < NROW / 256; ++it) {
    f32x4 v = __builtin_nontemporal_load(&ar[it * 64 + lane]);
    s += (v.x + v.y) + (v.z + v.w);
  }
  #pragma unroll
  for (int off = 32; off > 0; off >>= 1) s += __shfl_down(s, off, 64);
  if (lane == 0) dv[row] = rsqrtf(1.f + s);
}

// ---- k2: W convert (mid-fallback path only) ----
__global__ __launch_bounds__(256) void k_convert_w(
    const float* __restrict__ W, unsigned short* __restrict__ WsT) {
  int idx = blockIdx.x * 256 + threadIdx.x;
  int k = idx >> 8, f = idx & 255;
  WsT[(size_t)f * INF + k] = f2bf(W[idx]);
}

// ---- k3: support GEMM, X read as fp32 + converted in-kernel ----
// C[f][m] = sum_k WsT[f][k]*X[m][k]; YT[f][m] = dv[m]*C. Tile 128(f) x 128(m).
__global__ __launch_bounds__(256, 2) void k_support_fx(
    const unsigned short* __restrict__ WsT,
    const float* __restrict__ X,
    const float* __restrict__ dv,
    unsigned short* __restrict__ YT) {
  __shared__ unsigned short lA[128 * 64];   // W-tile, cp16-staged (swizzled)
  __shared__ unsigned short lB[128 * 64];   // X-tile, ds_write-staged (same swizzle)
  const int t = threadIdx.x;
  const int w = t >> 6, lane = t & 63;
  const int m0 = blockIdx.x * 128;   // feature tile
  const int n0 = blockIdx.y * 128;   // node tile
  const int rsub = lane >> 3, csub = lane & 7, swz = csub ^ rsub;
  const int lr = lane & 15, lq = lane >> 4, x7 = lane & 7;
  const int mw = (w >> 1) * 64, nw = (w & 1) * 64;

  const int xrow = t >> 1, xhalf = t & 1;
  const float4* xsrc = (const float4*)(X + (size_t)(n0 + xrow) * INF + xhalf * 32);

  f32x4 acc[4][4];
  #pragma unroll
  for (int i = 0; i < 4; ++i)
    #pragma unroll
    for (int j = 0; j < 4; ++j) acc[i][j] = f32x4{0.f, 0.f, 0.f, 0.f};

  const unsigned short* ga0 = WsT + (size_t)(m0 + w * 8 + rsub) * INF + swz * 8;

  for (int it = 0; it < INF / 64; ++it) {
    __syncthreads();
    #pragma unroll
    for (int i = 0; i < 4; ++i)
      async_cp16(ga0 + (size_t)(i * 32) * INF + it * 64, &lA[(i * 32 + w * 8) * 64]);
    #pragma unroll
    for (int u = 0; u < 8; ++u) {
      float4 v = xsrc[it * 16 + u];           // k = it*64 + xhalf*32 + u*4
      ushort4 b;
      b.x = f2bf(v.x); b.y = f2bf(v.y); b.z = f2bf(v.z); b.w = f2bf(v.w);
      int k = xhalf * 32 + u * 4;
      int chunk = k >> 3, klo = k & 7;
      int slot = chunk ^ (xrow & 7);          // LDS[r][s] = G[r][s^(r&7)]
      *(ushort4*)&lB[xrow * 64 + (slot << 3) + klo] = b;
    }
    __syncthreads();
    #pragma unroll
    for (int ks = 0; ks < 2; ++ks) {
      bf16x8 af[4], bfv[4];
      #pragma unroll
      for (int mi = 0; mi < 4; ++mi)
        af[mi] = *(const bf16x8*)&lA[(mw + mi * 16 + lr) * 64 + (((ks * 4 + lq) ^ x7) << 3)];
      #pragma unroll
      for (int ni = 0; ni < 4; ++ni)
        bfv[ni] = *(const bf16x8*)&lB[(nw + ni * 16 + lr) * 64 + (((ks * 4 + lq) ^ x7) << 3)];
      #pragma unroll
      for (int mi = 0; mi < 4; ++mi)
        #pragma unroll
        for (int ni = 0; ni < 4; ++ni)
          acc[mi][ni] = __builtin_amdgcn_mfma_f32_16x16x32_bf16(
              af[mi], bfv[ni], acc[mi][ni], 0, 0, 0);
    }
  }
  #pragma unroll
  for (int mi = 0; mi < 4; ++mi) {
    #pragma unroll
    for (int ni = 0; ni < 4; ++ni) {
      f32x4 a = acc[mi][ni];
      int gr0 = m0 + mw + mi * 16 + lq * 4;    // feature
      int gc  = n0 + nw + ni * 16 + lr;        // node
      float dd = dv[gc];
      #pragma unroll
      for (int r = 0; r < 4; ++r)
        YT[(size_t)(gr0 + r) * NROW + gc] = f2bf(dd * a[r]);
    }
  }
}

// ==== k4 v2: 512-thread, 8-wave, double-buffered 2-phase pipelined main GEMM ====
// P[z][m][f] = bf16( sum_{k in z-slice} Abf[m][k]*YT[f][k] )
// Tile 128(m) x 256(f), BK=64, split-K=8. LDS = 2 x (16+32) KB = 96 KB -> 1 block/CU,
// 8 waves (same TLP as old 2x4). STAGE of tile t+1 is issued BEFORE compute of tile t,
// so global-load latency hides under the MFMA phase instead of the barrier drain.
// Four DISTINCT __shared__ arrays so alias analysis cannot force vmcnt(0) before ds_read.

__device__ __forceinline__ void g_stage(
    const unsigned short* ga, const unsigned short* gb, int it,
    unsigned short* dA, unsigned short* dB, int w) {
  #pragma unroll
  for (int i = 0; i < 2; ++i)
    async_cp16(ga + (size_t)(i * 64) * NROW + it * 64, &dA[(i * 64 + w * 8) * 64]);
  #pragma unroll
  for (int i = 0; i < 4; ++i)
    async_cp16(gb + (size_t)(i * 64) * NROW + it * 64, &dB[(i * 64 + w * 8) * 64]);
}

__device__ __forceinline__ void g_compute(
    const unsigned short* sA, const unsigned short* sB,
    f32x4 (&acc)[4][4], int mw, int nw, int lr, int lq, int x7) {
  #pragma unroll
  for (int ks = 0; ks < 2; ++ks) {
    bf16x8 af[4], bfv[4];
    #pragma unroll
    for (int mi = 0; mi < 4; ++mi)
      af[mi] = *(const bf16x8*)&sA[(mw + mi * 16 + lr) * 64 + (((ks * 4 + lq) ^ x7) << 3)];
    #pragma unroll
    for (int ni = 0; ni < 4; ++ni)
      bfv[ni] = *(const bf16x8*)&sB[(nw + ni * 16 + lr) * 64 + (((ks * 4 + lq) ^ x7) << 3)];
    #pragma unroll
    for (int mi = 0; mi < 4; ++mi)
      #pragma unroll
      for (int ni = 0; ni < 4; ++ni)
        acc[mi][ni] = __builtin_amdgcn_mfma_f32_16x16x32_bf16(
            af[mi], bfv[ni], acc[mi][ni], 0, 0, 0);
  }
}

__global__ __launch_bounds__(512, 2) void k_gemm_main_v2(
    const unsigned short* __restrict__ Abf,  // [8192][8192] bf16 (L3-resident)
    const unsigned short* __restrict__ YT,   // [256][8192] bf16
    unsigned short* __restrict__ P) {        // [8][8192][256] bf16
  __shared__ unsigned short lA0[128 * 64];   // 16 KB
  __shared__ unsigned short lB0[256 * 64];   // 32 KB
  __shared__ unsigned short lA1[128 * 64];   // 16 KB
  __shared__ unsigned short lB1[256 * 64];   // 32 KB
  const int t = threadIdx.x;
  const int w = t >> 6, lane = t & 63;       // 8 waves
  const int m0 = blockIdx.x * 128;
  const int kz = blockIdx.y * 1024;
  const int rsub = lane >> 3, csub = lane & 7, swz = csub ^ rsub;
  const int lr = lane & 15, lq = lane >> 4, x7 = lane & 7;
  const int mw = (w & 1) * 64;               // wave m-offset (2)
  const int nw = (w >> 1) * 64;              // wave n-offset (4)

  f32x4 acc[4][4];
  #pragma unroll
  for (int i = 0; i < 4; ++i)
    #pragma unroll
    for (int j = 0; j < 4; ++j) acc[i][j] = f32x4{0.f, 0.f, 0.f, 0.f};

  // Pre-swizzled per-lane global sources (LDS[r][slot] = G[r][slot^(r&7)], rsub == r&7).
  const unsigned short* ga0 = Abf + (size_t)(m0 + w * 8 + rsub) * NROW + kz + swz * 8;
  const unsigned short* gb0 = YT + (size_t)(w * 8 + rsub) * NROW + kz + swz * 8;

  // prologue: stage tile 0 into buf0
  g_stage(ga0, gb0, 0, lA0, lB0, w);
  __syncthreads();                            // drains vmcnt -> buf0 ready

  #pragma unroll 1
  for (int t2 = 0; t2 < 8; ++t2) {
    int it = 2 * t2;
    // phase A: stage it+1 into buf1, compute it from buf0
    g_stage(ga0, gb0, it + 1, lA1, lB1, w);
    g_compute(lA0, lB0, acc, mw, nw, lr, lq, x7);
    __syncthreads();                          // buf1 ready; all waves done with buf0
    // phase B: stage it+2 into buf0, compute it+1 from buf1
    if (t2 < 7) g_stage(ga0, gb0, it + 2, lA0, lB0, w);
    g_compute(lA1, lB1, acc, mw, nw, lr, lq, x7);
    __syncthreads();                          // buf0 ready; all waves done with buf1
  }

  unsigned short* Pz = P + (size_t)blockIdx.y * NROW * OUTF;
  #pragma unroll
  for (int mi = 0; mi < 4; ++mi) {
    #pragma unroll
    for (int ni = 0; ni < 4; ++ni) {
      f32x4 a = acc[mi][ni];
      int gr0 = m0 + mw + mi * 16 + lq * 4;
      int gc  = nw + ni * 16 + lr;
      #pragma unroll
      for (int r = 0; r < 4; ++r)
        Pz[(size_t)(gr0 + r) * OUTF + gc] = f2bf_fast(a[r]);
    }
  }
}

// ---- k4-old: main GEMM reading A fp32 directly (mid-fallback when ws lacks Abf room) ----
__global__ __launch_bounds__(256, 2) void k_gemm_main_f32a(
    const float* __restrict__ A,
    const unsigned short* __restrict__ YT,
    unsigned short* __restrict__ P) {
  __shared__ unsigned short lA[128 * 64];
  __shared__ unsigned short lB[256 * 64];
  const int t = threadIdx.x;
  const int w = t >> 6, lane = t & 63;
  const int m0 = blockIdx.x * 128;
  const int kz = blockIdx.y * 1024;
  const int rsub = lane >> 3, csub = lane & 7, swz = csub ^ rsub;
  const int lr = lane & 15, lq = lane >> 4, x7 = lane & 7;
  const int mw = (w & 1) * 64;
  const int nw = (w >> 1) * 128;

  const int arow = t >> 2, aq = t & 3;
  const int aklo = (aq & 1) * 4;

  f32x4 acc[4][8];
  #pragma unroll
  for (int i = 0; i < 4; ++i)
    #pragma unroll
    for (int j = 0; j < 8; ++j) acc[i][j] = f32x4{0.f, 0.f, 0.f, 0.f};

  const unsigned short* gb0 = YT + (size_t)(w * 8 + rsub) * NROW + kz + swz * 8;

  for (int it = 0; it < 16; ++it) {
    __syncthreads();
    #pragma unroll
    for (int i = 0; i < 8; ++i)
      async_cp16(gb0 + (size_t)(i * 32) * NROW + it * 64, &lB[(i * 32 + w * 8) * 64]);
    #pragma unroll
    for (int h = 0; h < 2; ++h) {
      int r = arow + h * 64;
      const float4* asrc = (const float4*)(A + (size_t)(m0 + r) * NROW + kz + it * 64);
      #pragma unroll
      for (int j = 0; j < 4; ++j) {
        float4 v = asrc[aq + 4 * j];
        ushort4 b;
        b.x = f2bf_fast(v.x); b.y = f2bf_fast(v.y);
        b.z = f2bf_fast(v.z); b.w = f2bf_fast(v.w);
        int chunk = (aq + 4 * j) >> 1;
        int slot = chunk ^ (r & 7);
        *(ushort4*)&lA[r * 64 + (slot << 3) + aklo] = b;
      }
    }
    __syncthreads();
    #pragma unroll
    for (int ks = 0; ks < 2; ++ks) {
      bf16x8 af[4], bfv[8];
      #pragma unroll
      for (int mi = 0; mi < 4; ++mi)
        af[mi] = *(const bf16x8*)&lA[(mw + mi * 16 + lr) * 64 + (((ks * 4 + lq) ^ x7) << 3)];
      #pragma unroll
      for (int ni = 0; ni < 8; ++ni)
        bfv[ni] = *(const bf16x8*)&lB[(nw + ni * 16 + lr) * 64 + (((ks * 4 + lq) ^ x7) << 3)];
      #pragma unroll
      for (int mi = 0; mi < 4; ++mi)
        #pragma unroll
        for (int ni = 0; ni < 8; ++ni)
          acc[mi][ni] = __builtin_amdgcn_mfma_f32_16x16x32_bf16(
              af[mi], bfv[ni], acc[mi][ni], 0, 0, 0);
    }
  }

  unsigned short* Pz = P + (size_t)blockIdx.y * NROW * OUTF;
  #pragma unroll
  for (int mi = 0; mi < 4; ++mi) {
    #pragma unroll
    for (int ni = 0; ni < 8; ++ni) {
      f32x4 a = acc[mi][ni];
      int gr0 = m0 + mw + mi * 16 + lq * 4;
      int gc  = nw + ni * 16 + lr;
      #pragma unroll
      for (int r = 0; r < 4; ++r)
        Pz[(size_t)(gr0 + r) * OUTF + gc] = f2bf_fast(a[r]);
    }
  }
}

// ---- k5: out[i][f] = d[i] * sum_z bf2f(P[z][i][f]) ----
__global__ __launch_bounds__(256) void k_reduce8(
    const ushort4* __restrict__ P4, const float* __restrict__ dv,
    float4* __restrict__ o4) {
  int q = blockIdx.x * 256 + threadIdx.x;   // NROW*OUTF/4 threads
  const int QT = NROW * OUTF / 4;
  float4 s = {0.f, 0.f, 0.f, 0.f};
  #pragma unroll
  for (int z = 0; z < 8; ++z) {
    ushort4 v = P4[(size_t)z * QT + q];
    s.x += bf2f(v.x); s.y += bf2f(v.y); s.z += bf2f(v.z); s.w += bf2f(v.w);
  }
  float dd = dv[q >> 6];
  s.x *= dd; s.y *= dd; s.z *= dd; s.w *= dd;
  o4[q] = s;
}

// ---- fallback (ws too small): fp32, slow but correct ----
__global__ __launch_bounds__(256) void k_support_naive(
    const float* __restrict__ X, const float* __restrict__ W,
    const float* __restrict__ dv, float* __restrict__ Y) {
  __shared__ float lX[INF];
  int i = blockIdx.x;
  for (int k = threadIdx.x; k < INF; k += 256) lX[k] = X[(size_t)i * INF + k];
  __syncthreads();
  int f = threadIdx.x;
  float s = 0.f;
  for (int k = 0; k < INF; ++k) s += lX[k] * W[(size_t)k * OUTF + f];
  Y[(size_t)i * OUTF + f] = dv[i] * s;
}

__global__ __launch_bounds__(256) void k_main_naive(
    const float* __restrict__ A, const float* __restrict__ Y,
    const float* __restrict__ dv, float* __restrict__ out) {
  __shared__ float lA[256];
  int i = blockIdx.x, f = threadIdx.x;
  float s = 0.f;
  for (int jb = 0; jb < NROW; jb += 256) {
    __syncthreads();
    lA[threadIdx.x] = A[(size_t)i * NROW + jb + threadIdx.x];
    __syncthreads();
    for (int jj = 0; jj < 256; ++jj) s += lA[jj] * Y[(size_t)(jb + jj) * OUTF + f];
  }
  out[(size_t)i * OUTF + f] = dv[i] * s;
}

extern "C" void kernel_launch(void* const* d_in, const int* in_sizes, int n_in,
                              void* d_out, int out_size, void* d_ws, size_t ws_size,
                              hipStream_t stream) {
  const float* A = (const float*)d_in[0];
  const float* X = (const float*)d_in[1];
  const float* W = (const float*)d_in[2];
  float* out = (float*)d_out;

  const size_t SZ_YT  = (size_t)OUTF * NROW * 2;       // 4 MiB
  const size_t SZ_WST = (size_t)OUTF * INF * 2;        // 256 KiB
  const size_t SZ_D   = (size_t)NROW * 4;              // 32 KiB
  const size_t SZ_P   = (size_t)8 * NROW * OUTF * 2;   // 32 MiB (bf16)
  const size_t SZ_ABF = (size_t)NROW * NROW * 2;       // 128 MiB (bf16 A)
  const size_t NEED_BASE = SZ_YT + SZ_WST + SZ_D + SZ_P;
  const size_t NEED_FULL = NEED_BASE + SZ_ABF;

  char* p = (char*)d_ws;
  if (ws_size >= NEED_FULL) {
    unsigned short* YT  = (unsigned short*)p; p += SZ_YT;
    unsigned short* WsT = (unsigned short*)p; p += SZ_WST;
    float* dv = (float*)p; p += SZ_D;
    unsigned short* P = (unsigned short*)p; p += SZ_P;
    unsigned short* Abf = (unsigned short*)p;

    k_rowsum_cvt_w<<<dim3(2048), dim3(256), 0, stream>>>(A, W, dv, Abf, WsT);
    k_support_fx<<<dim3(2, 64), dim3(256), 0, stream>>>(WsT, X, dv, YT);
    k_gemm_main_v2<<<dim3(64, 8), dim3(512), 0, stream>>>(Abf, YT, P);
    k_reduce8<<<dim3(2048), dim3(256), 0, stream>>>((const ushort4*)P, dv, (float4*)out);
  } else if (ws_size >= NEED_BASE) {
    unsigned short* YT  = (unsigned short*)p; p += SZ_YT;
    unsigned short* WsT = (unsigned short*)p; p += SZ_WST;
    float* dv = (float*)p; p += SZ_D;
    unsigned short* P = (unsigned short*)p;

    k_convert_w<<<dim3(512), dim3(256), 0, stream>>>(W, WsT);
    k_rowsum<<<dim3(2048), dim3(256), 0, stream>>>(A, dv);
    k_support_fx<<<dim3(2, 64), dim3(256), 0, stream>>>(WsT, X, dv, YT);
    k_gemm_main_f32a<<<dim3(64, 8), dim3(256), 0, stream>>>(A, YT, P);
    k_reduce8<<<dim3(2048), dim3(256), 0, stream>>>((const ushort4*)P, dv, (float4*)out);
  } else {
    float* dv = (float*)p; p += SZ_D;
    float* Y  = (float*)p;
    k_rowsum<<<dim3(2048), dim3(256), 0, stream>>>(A, dv);
    k_support_naive<<<dim3(8192), dim3(256), 0, stream>>>(X, W, dv, Y);
    k_main_naive<<<dim3(8192), dim3(256), 0, stream>>>(A, Y, dv, out);
  }
}

// Round 5
// 433.825 us; speedup vs baseline: 1.0102x; 1.0102x over previous
//
#include <hip/hip_runtime.h>
#include <hip/hip_bf16.h>
#include <stdint.h>

#define NROW 8192
#define INF  512
#define OUTF 256

typedef __attribute__((ext_vector_type(8))) short bf16x8;
typedef __attribute__((ext_vector_type(4))) float f32x4;

__device__ __forceinline__ unsigned short f2bf(float x) {
  union { float f; unsigned u; } v; v.f = x;
  unsigned r = v.u + 0x7fffu + ((v.u >> 16) & 1u);   // RNE
  return (unsigned short)(r >> 16);
}
__device__ __forceinline__ unsigned short f2bf_fast(float x) {
  union { float f; unsigned u; } v; v.f = x;
  return (unsigned short)((v.u + 0x8000u) >> 16);    // round-half-up
}
__device__ __forceinline__ float bf2f(unsigned short h) {
  union { unsigned u; float f; } v; v.u = ((unsigned)h) << 16;
  return v.f;
}

__device__ __forceinline__ void async_cp16(const void* g, void* l) {
  __builtin_amdgcn_global_load_lds((const __attribute__((address_space(1))) void*)g,
                                   (__attribute__((address_space(3))) void*)l,
                                   16, 0, 0);
}

// ---- k1: rowsum + A->bf16 convert + W->WsT convert, one kernel ----
// A reads NON-TEMPORAL so the freshly written Abf (134 MB) stays L3-resident
// for k4's re-read (proven -22us in r3). Blocks 0..511 also convert one W
// element each (replaces the separate k_convert_w dispatch).
__global__ __launch_bounds__(256) void k_rowsum_cvt_w(
    const float* __restrict__ A, const float* __restrict__ W,
    float* __restrict__ dv, unsigned short* __restrict__ Abf,
    unsigned short* __restrict__ WsT) {
  if (blockIdx.x < 512) {
    int idx = blockIdx.x * 256 + threadIdx.x;   // 512*256 W elems
    int k = idx >> 8, f = idx & 255;
    WsT[(size_t)f * INF + k] = f2bf(W[idx]);
  }
  int w = threadIdx.x >> 6, lane = threadIdx.x & 63;
  int row = blockIdx.x * 4 + w;
  const f32x4* ar = (const f32x4*)(A + (size_t)row * NROW);
  ushort4* br = (ushort4*)(Abf + (size_t)row * NROW);
  float s = 0.f;
  #pragma unroll 4
  for (int it = 0; it < NROW / 256; ++it) {
    f32x4 v = __builtin_nontemporal_load(&ar[it * 64 + lane]);
    s += (v.x + v.y) + (v.z + v.w);
    ushort4 b;
    b.x = f2bf(v.x); b.y = f2bf(v.y); b.z = f2bf(v.z); b.w = f2bf(v.w);
    br[it * 64 + lane] = b;                // normal store: keep Abf in L3
  }
  #pragma unroll
  for (int off = 32; off > 0; off >>= 1) s += __shfl_down(s, off, 64);
  if (lane == 0) dv[row] = rsqrtf(1.f + s);
}

// ---- k1b: plain rowsum (mid-fallback path) ----
__global__ __launch_bounds__(256) void k_rowsum(
    const float* __restrict__ A, float* __restrict__ dv) {
  int w = threadIdx.x >> 6, lane = threadIdx.x & 63;
  int row = blockIdx.x * 4 + w;
  const f32x4* ar = (const f32x4*)(A + (size_t)row * NROW);
  float s = 0.f;
  #pragma unroll 4
  for (int it = 0; it < NROW / 256; ++it) {
    f32x4 v = __builtin_nontemporal_load(&ar[it * 64 + lane]);
    s += (v.x + v.y) + (v.z + v.w);
  }
  #pragma unroll
  for (int off = 32; off > 0; off >>= 1) s += __shfl_down(s, off, 64);
  if (lane == 0) dv[row] = rsqrtf(1.f + s);
}

// ---- k2: W convert (mid-fallback path only) ----
__global__ __launch_bounds__(256) void k_convert_w(
    const float* __restrict__ W, unsigned short* __restrict__ WsT) {
  int idx = blockIdx.x * 256 + threadIdx.x;
  int k = idx >> 8, f = idx & 255;
  WsT[(size_t)f * INF + k] = f2bf(W[idx]);
}

// ---- k3: support GEMM, X read as fp32 + converted in-kernel ----
// C[f][m] = sum_k WsT[f][k]*X[m][k]; YT[f][m] = dv[m]*C. Tile 128(f) x 128(m).
__global__ __launch_bounds__(256, 2) void k_support_fx(
    const unsigned short* __restrict__ WsT,
    const float* __restrict__ X,
    const float* __restrict__ dv,
    unsigned short* __restrict__ YT) {
  __shared__ unsigned short lA[128 * 64];   // W-tile, cp16-staged (swizzled)
  __shared__ unsigned short lB[128 * 64];   // X-tile, ds_write-staged (same swizzle)
  const int t = threadIdx.x;
  const int w = t >> 6, lane = t & 63;
  const int m0 = blockIdx.x * 128;   // feature tile
  const int n0 = blockIdx.y * 128;   // node tile
  const int rsub = lane >> 3, csub = lane & 7, swz = csub ^ rsub;
  const int lr = lane & 15, lq = lane >> 4, x7 = lane & 7;
  const int mw = (w >> 1) * 64, nw = (w & 1) * 64;

  const int xrow = t >> 1, xhalf = t & 1;
  const float4* xsrc = (const float4*)(X + (size_t)(n0 + xrow) * INF + xhalf * 32);

  f32x4 acc[4][4];
  #pragma unroll
  for (int i = 0; i < 4; ++i)
    #pragma unroll
    for (int j = 0; j < 4; ++j) acc[i][j] = f32x4{0.f, 0.f, 0.f, 0.f};

  const unsigned short* ga0 = WsT + (size_t)(m0 + w * 8 + rsub) * INF + swz * 8;

  for (int it = 0; it < INF / 64; ++it) {
    __syncthreads();
    #pragma unroll
    for (int i = 0; i < 4; ++i)
      async_cp16(ga0 + (size_t)(i * 32) * INF + it * 64, &lA[(i * 32 + w * 8) * 64]);
    #pragma unroll
    for (int u = 0; u < 8; ++u) {
      float4 v = xsrc[it * 16 + u];           // k = it*64 + xhalf*32 + u*4
      ushort4 b;
      b.x = f2bf(v.x); b.y = f2bf(v.y); b.z = f2bf(v.z); b.w = f2bf(v.w);
      int k = xhalf * 32 + u * 4;
      int chunk = k >> 3, klo = k & 7;
      int slot = chunk ^ (xrow & 7);          // LDS[r][s] = G[r][s^(r&7)]
      *(ushort4*)&lB[xrow * 64 + (slot << 3) + klo] = b;
    }
    __syncthreads();
    #pragma unroll
    for (int ks = 0; ks < 2; ++ks) {
      bf16x8 af[4], bfv[4];
      #pragma unroll
      for (int mi = 0; mi < 4; ++mi)
        af[mi] = *(const bf16x8*)&lA[(mw + mi * 16 + lr) * 64 + (((ks * 4 + lq) ^ x7) << 3)];
      #pragma unroll
      for (int ni = 0; ni < 4; ++ni)
        bfv[ni] = *(const bf16x8*)&lB[(nw + ni * 16 + lr) * 64 + (((ks * 4 + lq) ^ x7) << 3)];
      #pragma unroll
      for (int mi = 0; mi < 4; ++mi)
        #pragma unroll
        for (int ni = 0; ni < 4; ++ni)
          acc[mi][ni] = __builtin_amdgcn_mfma_f32_16x16x32_bf16(
              af[mi], bfv[ni], acc[mi][ni], 0, 0, 0);
    }
  }
  #pragma unroll
  for (int mi = 0; mi < 4; ++mi) {
    #pragma unroll
    for (int ni = 0; ni < 4; ++ni) {
      f32x4 a = acc[mi][ni];
      int gr0 = m0 + mw + mi * 16 + lq * 4;    // feature
      int gc  = n0 + nw + ni * 16 + lr;        // node
      float dd = dv[gc];
      #pragma unroll
      for (int r = 0; r < 4; ++r)
        YT[(size_t)(gr0 + r) * NROW + gc] = f2bf(dd * a[r]);
    }
  }
}

// ---- k4: main GEMM (round-3 proven version: 256 thr, 2 blocks/CU, inter-block overlap) ----
// P[z][m][f] = bf16( sum_{k in z-slice} Abf[m][k]*YT[f][k] ), tile 128x256, split-K=8
__global__ __launch_bounds__(256, 2) void k_gemm_main_bf16a(
    const unsigned short* __restrict__ Abf,  // [8192][8192] bf16 row-major (L3-resident)
    const unsigned short* __restrict__ YT,   // [256][8192] bf16
    unsigned short* __restrict__ P) {        // [8][8192][256] bf16
  __shared__ unsigned short lA[128 * 64];    // 16 KB
  __shared__ unsigned short lB[256 * 64];    // 32 KB
  const int t = threadIdx.x;
  const int w = t >> 6, lane = t & 63;
  const int m0 = blockIdx.x * 128;
  const int kz = blockIdx.y * 1024;
  const int rsub = lane >> 3, csub = lane & 7, swz = csub ^ rsub;
  const int lr = lane & 15, lq = lane >> 4, x7 = lane & 7;
  const int mw = (w & 1) * 64;               // wave m-offset
  const int nw = (w >> 1) * 128;             // wave n-offset

  f32x4 acc[4][8];
  #pragma unroll
  for (int i = 0; i < 4; ++i)
    #pragma unroll
    for (int j = 0; j < 8; ++j) acc[i][j] = f32x4{0.f, 0.f, 0.f, 0.f};

  // Pre-swizzled per-lane global sources; LDS dests are wave-uniform + lane*16
  // (LDS[r][slot] = G[r][slot ^ (r&7)], r&7 == rsub for all staged sub-rows).
  const unsigned short* ga0 = Abf + (size_t)(m0 + w * 8 + rsub) * NROW + kz + swz * 8;
  const unsigned short* gb0 = YT + (size_t)(w * 8 + rsub) * NROW + kz + swz * 8;

  for (int it = 0; it < 16; ++it) {
    __syncthreads();
    #pragma unroll
    for (int i = 0; i < 8; ++i)
      async_cp16(gb0 + (size_t)(i * 32) * NROW + it * 64, &lB[(i * 32 + w * 8) * 64]);
    #pragma unroll
    for (int i = 0; i < 4; ++i)
      async_cp16(ga0 + (size_t)(i * 32) * NROW + it * 64, &lA[(i * 32 + w * 8) * 64]);
    __syncthreads();
    #pragma unroll
    for (int ks = 0; ks < 2; ++ks) {
      bf16x8 af[4], bfv[8];
      #pragma unroll
      for (int mi = 0; mi < 4; ++mi)
        af[mi] = *(const bf16x8*)&lA[(mw + mi * 16 + lr) * 64 + (((ks * 4 + lq) ^ x7) << 3)];
      #pragma unroll
      for (int ni = 0; ni < 8; ++ni)
        bfv[ni] = *(const bf16x8*)&lB[(nw + ni * 16 + lr) * 64 + (((ks * 4 + lq) ^ x7) << 3)];
      #pragma unroll
      for (int mi = 0; mi < 4; ++mi)
        #pragma unroll
        for (int ni = 0; ni < 8; ++ni)
          acc[mi][ni] = __builtin_amdgcn_mfma_f32_16x16x32_bf16(
              af[mi], bfv[ni], acc[mi][ni], 0, 0, 0);
    }
  }

  unsigned short* Pz = P + (size_t)blockIdx.y * NROW * OUTF;
  #pragma unroll
  for (int mi = 0; mi < 4; ++mi) {
    #pragma unroll
    for (int ni = 0; ni < 8; ++ni) {
      f32x4 a = acc[mi][ni];
      int gr0 = m0 + mw + mi * 16 + lq * 4;
      int gc  = nw + ni * 16 + lr;
      #pragma unroll
      for (int r = 0; r < 4; ++r)
        Pz[(size_t)(gr0 + r) * OUTF + gc] = f2bf_fast(a[r]);
    }
  }
}

// ---- k4-old: main GEMM reading A fp32 directly (mid-fallback when ws lacks Abf room) ----
__global__ __launch_bounds__(256, 2) void k_gemm_main_f32a(
    const float* __restrict__ A,
    const unsigned short* __restrict__ YT,
    unsigned short* __restrict__ P) {
  __shared__ unsigned short lA[128 * 64];
  __shared__ unsigned short lB[256 * 64];
  const int t = threadIdx.x;
  const int w = t >> 6, lane = t & 63;
  const int m0 = blockIdx.x * 128;
  const int kz = blockIdx.y * 1024;
  const int rsub = lane >> 3, csub = lane & 7, swz = csub ^ rsub;
  const int lr = lane & 15, lq = lane >> 4, x7 = lane & 7;
  const int mw = (w & 1) * 64;
  const int nw = (w >> 1) * 128;

  const int arow = t >> 2, aq = t & 3;
  const int aklo = (aq & 1) * 4;

  f32x4 acc[4][8];
  #pragma unroll
  for (int i = 0; i < 4; ++i)
    #pragma unroll
    for (int j = 0; j < 8; ++j) acc[i][j] = f32x4{0.f, 0.f, 0.f, 0.f};

  const unsigned short* gb0 = YT + (size_t)(w * 8 + rsub) * NROW + kz + swz * 8;

  for (int it = 0; it < 16; ++it) {
    __syncthreads();
    #pragma unroll
    for (int i = 0; i < 8; ++i)
      async_cp16(gb0 + (size_t)(i * 32) * NROW + it * 64, &lB[(i * 32 + w * 8) * 64]);
    #pragma unroll
    for (int h = 0; h < 2; ++h) {
      int r = arow + h * 64;
      const float4* asrc = (const float4*)(A + (size_t)(m0 + r) * NROW + kz + it * 64);
      #pragma unroll
      for (int j = 0; j < 4; ++j) {
        float4 v = asrc[aq + 4 * j];
        ushort4 b;
        b.x = f2bf_fast(v.x); b.y = f2bf_fast(v.y);
        b.z = f2bf_fast(v.z); b.w = f2bf_fast(v.w);
        int chunk = (aq + 4 * j) >> 1;
        int slot = chunk ^ (r & 7);
        *(ushort4*)&lA[r * 64 + (slot << 3) + aklo] = b;
      }
    }
    __syncthreads();
    #pragma unroll
    for (int ks = 0; ks < 2; ++ks) {
      bf16x8 af[4], bfv[8];
      #pragma unroll
      for (int mi = 0; mi < 4; ++mi)
        af[mi] = *(const bf16x8*)&lA[(mw + mi * 16 + lr) * 64 + (((ks * 4 + lq) ^ x7) << 3)];
      #pragma unroll
      for (int ni = 0; ni < 8; ++ni)
        bfv[ni] = *(const bf16x8*)&lB[(nw + ni * 16 + lr) * 64 + (((ks * 4 + lq) ^ x7) << 3)];
      #pragma unroll
      for (int mi = 0; mi < 4; ++mi)
        #pragma unroll
        for (int ni = 0; ni < 8; ++ni)
          acc[mi][ni] = __builtin_amdgcn_mfma_f32_16x16x32_bf16(
              af[mi], bfv[ni], acc[mi][ni], 0, 0, 0);
    }
  }

  unsigned short* Pz = P + (size_t)blockIdx.y * NROW * OUTF;
  #pragma unroll
  for (int mi = 0; mi < 4; ++mi) {
    #pragma unroll
    for (int ni = 0; ni < 8; ++ni) {
      f32x4 a = acc[mi][ni];
      int gr0 = m0 + mw + mi * 16 + lq * 4;
      int gc  = nw + ni * 16 + lr;
      #pragma unroll
      for (int r = 0; r < 4; ++r)
        Pz[(size_t)(gr0 + r) * OUTF + gc] = f2bf_fast(a[r]);
    }
  }
}

// ---- k5: out[i][f] = d[i] * sum_z bf2f(P[z][i][f]) ----
__global__ __launch_bounds__(256) void k_reduce8(
    const ushort4* __restrict__ P4, const float* __restrict__ dv,
    float4* __restrict__ o4) {
  int q = blockIdx.x * 256 + threadIdx.x;   // NROW*OUTF/4 threads
  const int QT = NROW * OUTF / 4;
  float4 s = {0.f, 0.f, 0.f, 0.f};
  #pragma unroll
  for (int z = 0; z < 8; ++z) {
    ushort4 v = P4[(size_t)z * QT + q];
    s.x += bf2f(v.x); s.y += bf2f(v.y); s.z += bf2f(v.z); s.w += bf2f(v.w);
  }
  float dd = dv[q >> 6];
  s.x *= dd; s.y *= dd; s.z *= dd; s.w *= dd;
  o4[q] = s;
}

// ---- fallback (ws too small): fp32, slow but correct ----
__global__ __launch_bounds__(256) void k_support_naive(
    const float* __restrict__ X, const float* __restrict__ W,
    const float* __restrict__ dv, float* __restrict__ Y) {
  __shared__ float lX[INF];
  int i = blockIdx.x;
  for (int k = threadIdx.x; k < INF; k += 256) lX[k] = X[(size_t)i * INF + k];
  __syncthreads();
  int f = threadIdx.x;
  float s = 0.f;
  for (int k = 0; k < INF; ++k) s += lX[k] * W[(size_t)k * OUTF + f];
  Y[(size_t)i * OUTF + f] = dv[i] * s;
}

__global__ __launch_bounds__(256) void k_main_naive(
    const float* __restrict__ A, const float* __restrict__ Y,
    const float* __restrict__ dv, float* __restrict__ out) {
  __shared__ float lA[256];
  int i = blockIdx.x, f = threadIdx.x;
  float s = 0.f;
  for (int jb = 0; jb < NROW; jb += 256) {
    __syncthreads();
    lA[threadIdx.x] = A[(size_t)i * NROW + jb + threadIdx.x];
    __syncthreads();
    for (int jj = 0; jj < 256; ++jj) s += lA[jj] * Y[(size_t)(jb + jj) * OUTF + f];
  }
  out[(size_t)i * OUTF + f] = dv[i] * s;
}

extern "C" void kernel_launch(void* const* d_in, const int* in_sizes, int n_in,
                              void* d_out, int out_size, void* d_ws, size_t ws_size,
                              hipStream_t stream) {
  const float* A = (const float*)d_in[0];
  const float* X = (const float*)d_in[1];
  const float* W = (const float*)d_in[2];
  float* out = (float*)d_out;

  const size_t SZ_YT  = (size_t)OUTF * NROW * 2;       // 4 MiB
  const size_t SZ_WST = (size_t)OUTF * INF * 2;        // 256 KiB
  const size_t SZ_D   = (size_t)NROW * 4;              // 32 KiB
  const size_t SZ_P   = (size_t)8 * NROW * OUTF * 2;   // 32 MiB (bf16)
  const size_t SZ_ABF = (size_t)NROW * NROW * 2;       // 128 MiB (bf16 A)
  const size_t NEED_BASE = SZ_YT + SZ_WST + SZ_D + SZ_P;
  const size_t NEED_FULL = NEED_BASE + SZ_ABF;

  char* p = (char*)d_ws;
  if (ws_size >= NEED_FULL) {
    unsigned short* YT  = (unsigned short*)p; p += SZ_YT;
    unsigned short* WsT = (unsigned short*)p; p += SZ_WST;
    float* dv = (float*)p; p += SZ_D;
    unsigned short* P = (unsigned short*)p; p += SZ_P;
    unsigned short* Abf = (unsigned short*)p;

    k_rowsum_cvt_w<<<dim3(2048), dim3(256), 0, stream>>>(A, W, dv, Abf, WsT);
    k_support_fx<<<dim3(2, 64), dim3(256), 0, stream>>>(WsT, X, dv, YT);
    k_gemm_main_bf16a<<<dim3(64, 8), dim3(256), 0, stream>>>(Abf, YT, P);
    k_reduce8<<<dim3(2048), dim3(256), 0, stream>>>((const ushort4*)P, dv, (float4*)out);
  } else if (ws_size >= NEED_BASE) {
    unsigned short* YT  = (unsigned short*)p; p += SZ_YT;
    unsigned short* WsT = (unsigned short*)p; p += SZ_WST;
    float* dv = (float*)p; p += SZ_D;
    unsigned short* P = (unsigned short*)p;

    k_convert_w<<<dim3(512), dim3(256), 0, stream>>>(W, WsT);
    k_rowsum<<<dim3(2048), dim3(256), 0, stream>>>(A, dv);
    k_support_fx<<<dim3(2, 64), dim3(256), 0, stream>>>(WsT, X, dv, YT);
    k_gemm_main_f32a<<<dim3(64, 8), dim3(256), 0, stream>>>(A, YT, P);
    k_reduce8<<<dim3(2048), dim3(256), 0, stream>>>((const ushort4*)P, dv, (float4*)out);
  } else {
    float* dv = (float*)p; p += SZ_D;
    float* Y  = (float*)p;
    k_rowsum<<<dim3(2048), dim3(256), 0, stream>>>(A, dv);
    k_support_naive<<<dim3(8192), dim3(256), 0, stream>>>(X, W, dv, Y);
    k_main_naive<<<dim3(8192), dim3(256), 0, stream>>>(A, Y, dv, out);
  }
}

// Round 6
// 425.188 us; speedup vs baseline: 1.0307x; 1.0203x over previous
//
#include <hip/hip_runtime.h>
#include <hip/hip_bf16.h>
#include <stdint.h>

#define NROW 8192
#define INF  512
#define OUTF 256

typedef __attribute__((ext_vector_type(8))) short bf16x8;
typedef __attribute__((ext_vector_type(4))) float f32x4;

__device__ __forceinline__ unsigned short f2bf(float x) {
  union { float f; unsigned u; } v; v.f = x;
  unsigned r = v.u + 0x7fffu + ((v.u >> 16) & 1u);   // RNE
  return (unsigned short)(r >> 16);
}
__device__ __forceinline__ unsigned short f2bf_fast(float x) {
  union { float f; unsigned u; } v; v.f = x;
  return (unsigned short)((v.u + 0x8000u) >> 16);    // round-half-up
}
__device__ __forceinline__ float bf2f(unsigned short h) {
  union { unsigned u; float f; } v; v.u = ((unsigned)h) << 16;
  return v.f;
}

__device__ __forceinline__ void async_cp16(const void* g, void* l) {
  __builtin_amdgcn_global_load_lds((const __attribute__((address_space(1))) void*)g,
                                   (__attribute__((address_space(3))) void*)l,
                                   16, 0, 0);
}

// ---- k1: rowsum + A->bf16 convert + W->WsT convert, one kernel ----
// A reads NON-TEMPORAL so the freshly written Abf (134 MB) stays L3-resident
// for k4's re-read (proven -22us in r3). Blocks 0..511 also convert one W
// element each (replaces the separate k_convert_w dispatch).
__global__ __launch_bounds__(256) void k_rowsum_cvt_w(
    const float* __restrict__ A, const float* __restrict__ W,
    float* __restrict__ dv, unsigned short* __restrict__ Abf,
    unsigned short* __restrict__ WsT) {
  if (blockIdx.x < 512) {
    int idx = blockIdx.x * 256 + threadIdx.x;   // 512*256 W elems
    int k = idx >> 8, f = idx & 255;
    WsT[(size_t)f * INF + k] = f2bf(W[idx]);
  }
  int w = threadIdx.x >> 6, lane = threadIdx.x & 63;
  int row = blockIdx.x * 4 + w;
  const f32x4* ar = (const f32x4*)(A + (size_t)row * NROW);
  ushort4* br = (ushort4*)(Abf + (size_t)row * NROW);
  float s = 0.f;
  #pragma unroll 4
  for (int it = 0; it < NROW / 256; ++it) {
    f32x4 v = __builtin_nontemporal_load(&ar[it * 64 + lane]);
    s += (v.x + v.y) + (v.z + v.w);
    ushort4 b;
    b.x = f2bf(v.x); b.y = f2bf(v.y); b.z = f2bf(v.z); b.w = f2bf(v.w);
    br[it * 64 + lane] = b;                // normal store: keep Abf in L3
  }
  #pragma unroll
  for (int off = 32; off > 0; off >>= 1) s += __shfl_down(s, off, 64);
  if (lane == 0) dv[row] = rsqrtf(1.f + s);
}

// ---- k1b: plain rowsum (mid-fallback path) ----
__global__ __launch_bounds__(256) void k_rowsum(
    const float* __restrict__ A, float* __restrict__ dv) {
  int w = threadIdx.x >> 6, lane = threadIdx.x & 63;
  int row = blockIdx.x * 4 + w;
  const f32x4* ar = (const f32x4*)(A + (size_t)row * NROW);
  float s = 0.f;
  #pragma unroll 4
  for (int it = 0; it < NROW / 256; ++it) {
    f32x4 v = __builtin_nontemporal_load(&ar[it * 64 + lane]);
    s += (v.x + v.y) + (v.z + v.w);
  }
  #pragma unroll
  for (int off = 32; off > 0; off >>= 1) s += __shfl_down(s, off, 64);
  if (lane == 0) dv[row] = rsqrtf(1.f + s);
}

// ---- k2: W convert (mid-fallback path only) ----
__global__ __launch_bounds__(256) void k_convert_w(
    const float* __restrict__ W, unsigned short* __restrict__ WsT) {
  int idx = blockIdx.x * 256 + threadIdx.x;
  int k = idx >> 8, f = idx & 255;
  WsT[(size_t)f * INF + k] = f2bf(W[idx]);
}

// ---- k3 v2: support GEMM, node-tile 64 -> grid (2,128) = 256 blocks (all CUs) ----
// C[f][m] = sum_k WsT[f][k]*X[m][k]; YT[f][m] = dv[m]*C. Tile 128(f) x 64(node).
// X staged fp32->bf16 with the proven f32a swizzle pattern; W via cp16 (unchanged).
__global__ __launch_bounds__(256, 2) void k_support_fx64(
    const unsigned short* __restrict__ WsT,
    const float* __restrict__ X,
    const float* __restrict__ dv,
    unsigned short* __restrict__ YT) {
  __shared__ unsigned short lA[128 * 64];   // W-tile, cp16-staged (swizzled), 16 KB
  __shared__ unsigned short lB[64 * 64];    // X-tile, ds_write-staged (same swizzle), 8 KB
  const int t = threadIdx.x;
  const int w = t >> 6, lane = t & 63;
  const int m0 = blockIdx.x * 128;   // feature tile (2)
  const int n0 = blockIdx.y * 64;    // node tile (128)
  const int rsub = lane >> 3, csub = lane & 7, swz = csub ^ rsub;
  const int lr = lane & 15, lq = lane >> 4, x7 = lane & 7;
  const int mw = (w & 1) * 64, nw = (w >> 1) * 32;   // wave tile 64f x 32n

  const int xrow = t >> 2, xq = t & 3;     // 64 X-rows, 4 threads/row
  const int xklo = (xq & 1) * 4;
  const float4* xsrc = (const float4*)(X + (size_t)(n0 + xrow) * INF);

  f32x4 acc[4][2];
  #pragma unroll
  for (int i = 0; i < 4; ++i)
    #pragma unroll
    for (int j = 0; j < 2; ++j) acc[i][j] = f32x4{0.f, 0.f, 0.f, 0.f};

  const unsigned short* ga0 = WsT + (size_t)(m0 + w * 8 + rsub) * INF + swz * 8;

  for (int it = 0; it < INF / 64; ++it) {
    __syncthreads();
    #pragma unroll
    for (int i = 0; i < 4; ++i)
      async_cp16(ga0 + (size_t)(i * 32) * INF + it * 64, &lA[(i * 32 + w * 8) * 64]);
    // X: 64 rows x 64 k fp32 -> bf16, swizzled: LDS[r][slot] = G[r][slot^(r&7)]
    #pragma unroll
    for (int j = 0; j < 4; ++j) {
      float4 v = xsrc[it * 16 + xq + 4 * j];          // k = (xq+4j)*4
      ushort4 b;
      b.x = f2bf(v.x); b.y = f2bf(v.y); b.z = f2bf(v.z); b.w = f2bf(v.w);
      int chunk = (xq + 4 * j) >> 1;
      int slot = chunk ^ (xrow & 7);
      *(ushort4*)&lB[xrow * 64 + (slot << 3) + xklo] = b;
    }
    __syncthreads();
    #pragma unroll
    for (int ks = 0; ks < 2; ++ks) {
      bf16x8 af[4], bfv[2];
      #pragma unroll
      for (int mi = 0; mi < 4; ++mi)
        af[mi] = *(const bf16x8*)&lA[(mw + mi * 16 + lr) * 64 + (((ks * 4 + lq) ^ x7) << 3)];
      #pragma unroll
      for (int ni = 0; ni < 2; ++ni)
        bfv[ni] = *(const bf16x8*)&lB[(nw + ni * 16 + lr) * 64 + (((ks * 4 + lq) ^ x7) << 3)];
      #pragma unroll
      for (int mi = 0; mi < 4; ++mi)
        #pragma unroll
        for (int ni = 0; ni < 2; ++ni)
          acc[mi][ni] = __builtin_amdgcn_mfma_f32_16x16x32_bf16(
              af[mi], bfv[ni], acc[mi][ni], 0, 0, 0);
    }
  }
  #pragma unroll
  for (int mi = 0; mi < 4; ++mi) {
    #pragma unroll
    for (int ni = 0; ni < 2; ++ni) {
      f32x4 a = acc[mi][ni];
      int gr0 = m0 + mw + mi * 16 + lq * 4;    // feature
      int gc  = n0 + nw + ni * 16 + lr;        // node
      float dd = dv[gc];
      #pragma unroll
      for (int r = 0; r < 4; ++r)
        YT[(size_t)(gr0 + r) * NROW + gc] = f2bf(dd * a[r]);
    }
  }
}

// ---- k3-old: 128x128 support GEMM (mid-fallback path only) ----
__global__ __launch_bounds__(256, 2) void k_support_fx(
    const unsigned short* __restrict__ WsT,
    const float* __restrict__ X,
    const float* __restrict__ dv,
    unsigned short* __restrict__ YT) {
  __shared__ unsigned short lA[128 * 64];
  __shared__ unsigned short lB[128 * 64];
  const int t = threadIdx.x;
  const int w = t >> 6, lane = t & 63;
  const int m0 = blockIdx.x * 128;
  const int n0 = blockIdx.y * 128;
  const int rsub = lane >> 3, csub = lane & 7, swz = csub ^ rsub;
  const int lr = lane & 15, lq = lane >> 4, x7 = lane & 7;
  const int mw = (w >> 1) * 64, nw = (w & 1) * 64;

  const int xrow = t >> 1, xhalf = t & 1;
  const float4* xsrc = (const float4*)(X + (size_t)(n0 + xrow) * INF + xhalf * 32);

  f32x4 acc[4][4];
  #pragma unroll
  for (int i = 0; i < 4; ++i)
    #pragma unroll
    for (int j = 0; j < 4; ++j) acc[i][j] = f32x4{0.f, 0.f, 0.f, 0.f};

  const unsigned short* ga0 = WsT + (size_t)(m0 + w * 8 + rsub) * INF + swz * 8;

  for (int it = 0; it < INF / 64; ++it) {
    __syncthreads();
    #pragma unroll
    for (int i = 0; i < 4; ++i)
      async_cp16(ga0 + (size_t)(i * 32) * INF + it * 64, &lA[(i * 32 + w * 8) * 64]);
    #pragma unroll
    for (int u = 0; u < 8; ++u) {
      float4 v = xsrc[it * 16 + u];
      ushort4 b;
      b.x = f2bf(v.x); b.y = f2bf(v.y); b.z = f2bf(v.z); b.w = f2bf(v.w);
      int k = xhalf * 32 + u * 4;
      int chunk = k >> 3, klo = k & 7;
      int slot = chunk ^ (xrow & 7);
      *(ushort4*)&lB[xrow * 64 + (slot << 3) + klo] = b;
    }
    __syncthreads();
    #pragma unroll
    for (int ks = 0; ks < 2; ++ks) {
      bf16x8 af[4], bfv[4];
      #pragma unroll
      for (int mi = 0; mi < 4; ++mi)
        af[mi] = *(const bf16x8*)&lA[(mw + mi * 16 + lr) * 64 + (((ks * 4 + lq) ^ x7) << 3)];
      #pragma unroll
      for (int ni = 0; ni < 4; ++ni)
        bfv[ni] = *(const bf16x8*)&lB[(nw + ni * 16 + lr) * 64 + (((ks * 4 + lq) ^ x7) << 3)];
      #pragma unroll
      for (int mi = 0; mi < 4; ++mi)
        #pragma unroll
        for (int ni = 0; ni < 4; ++ni)
          acc[mi][ni] = __builtin_amdgcn_mfma_f32_16x16x32_bf16(
              af[mi], bfv[ni], acc[mi][ni], 0, 0, 0);
    }
  }
  #pragma unroll
  for (int mi = 0; mi < 4; ++mi) {
    #pragma unroll
    for (int ni = 0; ni < 4; ++ni) {
      f32x4 a = acc[mi][ni];
      int gr0 = m0 + mw + mi * 16 + lq * 4;
      int gc  = n0 + nw + ni * 16 + lr;
      float dd = dv[gc];
      #pragma unroll
      for (int r = 0; r < 4; ++r)
        YT[(size_t)(gr0 + r) * NROW + gc] = f2bf(dd * a[r]);
    }
  }
}

// ---- k4: main GEMM (round-3 proven version: 256 thr, 2 blocks/CU, inter-block overlap) ----
// P[z][m][f] = bf16( sum_{k in z-slice} Abf[m][k]*YT[f][k] ), tile 128x256, split-K=8
__global__ __launch_bounds__(256, 2) void k_gemm_main_bf16a(
    const unsigned short* __restrict__ Abf,  // [8192][8192] bf16 row-major (L3-resident)
    const unsigned short* __restrict__ YT,   // [256][8192] bf16
    unsigned short* __restrict__ P) {        // [8][8192][256] bf16
  __shared__ unsigned short lA[128 * 64];    // 16 KB
  __shared__ unsigned short lB[256 * 64];    // 32 KB
  const int t = threadIdx.x;
  const int w = t >> 6, lane = t & 63;
  const int m0 = blockIdx.x * 128;
  const int kz = blockIdx.y * 1024;
  const int rsub = lane >> 3, csub = lane & 7, swz = csub ^ rsub;
  const int lr = lane & 15, lq = lane >> 4, x7 = lane & 7;
  const int mw = (w & 1) * 64;               // wave m-offset
  const int nw = (w >> 1) * 128;             // wave n-offset

  f32x4 acc[4][8];
  #pragma unroll
  for (int i = 0; i < 4; ++i)
    #pragma unroll
    for (int j = 0; j < 8; ++j) acc[i][j] = f32x4{0.f, 0.f, 0.f, 0.f};

  // Pre-swizzled per-lane global sources; LDS dests are wave-uniform + lane*16
  // (LDS[r][slot] = G[r][slot ^ (r&7)], r&7 == rsub for all staged sub-rows).
  const unsigned short* ga0 = Abf + (size_t)(m0 + w * 8 + rsub) * NROW + kz + swz * 8;
  const unsigned short* gb0 = YT + (size_t)(w * 8 + rsub) * NROW + kz + swz * 8;

  for (int it = 0; it < 16; ++it) {
    __syncthreads();
    #pragma unroll
    for (int i = 0; i < 8; ++i)
      async_cp16(gb0 + (size_t)(i * 32) * NROW + it * 64, &lB[(i * 32 + w * 8) * 64]);
    #pragma unroll
    for (int i = 0; i < 4; ++i)
      async_cp16(ga0 + (size_t)(i * 32) * NROW + it * 64, &lA[(i * 32 + w * 8) * 64]);
    __syncthreads();
    #pragma unroll
    for (int ks = 0; ks < 2; ++ks) {
      bf16x8 af[4], bfv[8];
      #pragma unroll
      for (int mi = 0; mi < 4; ++mi)
        af[mi] = *(const bf16x8*)&lA[(mw + mi * 16 + lr) * 64 + (((ks * 4 + lq) ^ x7) << 3)];
      #pragma unroll
      for (int ni = 0; ni < 8; ++ni)
        bfv[ni] = *(const bf16x8*)&lB[(nw + ni * 16 + lr) * 64 + (((ks * 4 + lq) ^ x7) << 3)];
      #pragma unroll
      for (int mi = 0; mi < 4; ++mi)
        #pragma unroll
        for (int ni = 0; ni < 8; ++ni)
          acc[mi][ni] = __builtin_amdgcn_mfma_f32_16x16x32_bf16(
              af[mi], bfv[ni], acc[mi][ni], 0, 0, 0);
    }
  }

  unsigned short* Pz = P + (size_t)blockIdx.y * NROW * OUTF;
  #pragma unroll
  for (int mi = 0; mi < 4; ++mi) {
    #pragma unroll
    for (int ni = 0; ni < 8; ++ni) {
      f32x4 a = acc[mi][ni];
      int gr0 = m0 + mw + mi * 16 + lq * 4;
      int gc  = nw + ni * 16 + lr;
      #pragma unroll
      for (int r = 0; r < 4; ++r)
        Pz[(size_t)(gr0 + r) * OUTF + gc] = f2bf_fast(a[r]);
    }
  }
}

// ---- k4-old: main GEMM reading A fp32 directly (mid-fallback when ws lacks Abf room) ----
__global__ __launch_bounds__(256, 2) void k_gemm_main_f32a(
    const float* __restrict__ A,
    const unsigned short* __restrict__ YT,
    unsigned short* __restrict__ P) {
  __shared__ unsigned short lA[128 * 64];
  __shared__ unsigned short lB[256 * 64];
  const int t = threadIdx.x;
  const int w = t >> 6, lane = t & 63;
  const int m0 = blockIdx.x * 128;
  const int kz = blockIdx.y * 1024;
  const int rsub = lane >> 3, csub = lane & 7, swz = csub ^ rsub;
  const int lr = lane & 15, lq = lane >> 4, x7 = lane & 7;
  const int mw = (w & 1) * 64;
  const int nw = (w >> 1) * 128;

  const int arow = t >> 2, aq = t & 3;
  const int aklo = (aq & 1) * 4;

  f32x4 acc[4][8];
  #pragma unroll
  for (int i = 0; i < 4; ++i)
    #pragma unroll
    for (int j = 0; j < 8; ++j) acc[i][j] = f32x4{0.f, 0.f, 0.f, 0.f};

  const unsigned short* gb0 = YT + (size_t)(w * 8 + rsub) * NROW + kz + swz * 8;

  for (int it = 0; it < 16; ++it) {
    __syncthreads();
    #pragma unroll
    for (int i = 0; i < 8; ++i)
      async_cp16(gb0 + (size_t)(i * 32) * NROW + it * 64, &lB[(i * 32 + w * 8) * 64]);
    #pragma unroll
    for (int h = 0; h < 2; ++h) {
      int r = arow + h * 64;
      const float4* asrc = (const float4*)(A + (size_t)(m0 + r) * NROW + kz + it * 64);
      #pragma unroll
      for (int j = 0; j < 4; ++j) {
        float4 v = asrc[aq + 4 * j];
        ushort4 b;
        b.x = f2bf_fast(v.x); b.y = f2bf_fast(v.y);
        b.z = f2bf_fast(v.z); b.w = f2bf_fast(v.w);
        int chunk = (aq + 4 * j) >> 1;
        int slot = chunk ^ (r & 7);
        *(ushort4*)&lA[r * 64 + (slot << 3) + aklo] = b;
      }
    }
    __syncthreads();
    #pragma unroll
    for (int ks = 0; ks < 2; ++ks) {
      bf16x8 af[4], bfv[8];
      #pragma unroll
      for (int mi = 0; mi < 4; ++mi)
        af[mi] = *(const bf16x8*)&lA[(mw + mi * 16 + lr) * 64 + (((ks * 4 + lq) ^ x7) << 3)];
      #pragma unroll
      for (int ni = 0; ni < 8; ++ni)
        bfv[ni] = *(const bf16x8*)&lB[(nw + ni * 16 + lr) * 64 + (((ks * 4 + lq) ^ x7) << 3)];
      #pragma unroll
      for (int mi = 0; mi < 4; ++mi)
        #pragma unroll
        for (int ni = 0; ni < 8; ++ni)
          acc[mi][ni] = __builtin_amdgcn_mfma_f32_16x16x32_bf16(
              af[mi], bfv[ni], acc[mi][ni], 0, 0, 0);
    }
  }

  unsigned short* Pz = P + (size_t)blockIdx.y * NROW * OUTF;
  #pragma unroll
  for (int mi = 0; mi < 4; ++mi) {
    #pragma unroll
    for (int ni = 0; ni < 8; ++ni) {
      f32x4 a = acc[mi][ni];
      int gr0 = m0 + mw + mi * 16 + lq * 4;
      int gc  = nw + ni * 16 + lr;
      #pragma unroll
      for (int r = 0; r < 4; ++r)
        Pz[(size_t)(gr0 + r) * OUTF + gc] = f2bf_fast(a[r]);
    }
  }
}

// ---- k5: out[i][f] = d[i] * sum_z bf2f(P[z][i][f]) ----
__global__ __launch_bounds__(256) void k_reduce8(
    const ushort4* __restrict__ P4, const float* __restrict__ dv,
    float4* __restrict__ o4) {
  int q = blockIdx.x * 256 + threadIdx.x;   // NROW*OUTF/4 threads
  const int QT = NROW * OUTF / 4;
  float4 s = {0.f, 0.f, 0.f, 0.f};
  #pragma unroll
  for (int z = 0; z < 8; ++z) {
    ushort4 v = P4[(size_t)z * QT + q];
    s.x += bf2f(v.x); s.y += bf2f(v.y); s.z += bf2f(v.z); s.w += bf2f(v.w);
  }
  float dd = dv[q >> 6];
  s.x *= dd; s.y *= dd; s.z *= dd; s.w *= dd;
  o4[q] = s;
}

// ---- fallback (ws too small): fp32, slow but correct ----
__global__ __launch_bounds__(256) void k_support_naive(
    const float* __restrict__ X, const float* __restrict__ W,
    const float* __restrict__ dv, float* __restrict__ Y) {
  __shared__ float lX[INF];
  int i = blockIdx.x;
  for (int k = threadIdx.x; k < INF; k += 256) lX[k] = X[(size_t)i * INF + k];
  __syncthreads();
  int f = threadIdx.x;
  float s = 0.f;
  for (int k = 0; k < INF; ++k) s += lX[k] * W[(size_t)k * OUTF + f];
  Y[(size_t)i * OUTF + f] = dv[i] * s;
}

__global__ __launch_bounds__(256) void k_main_naive(
    const float* __restrict__ A, const float* __restrict__ Y,
    const float* __restrict__ dv, float* __restrict__ out) {
  __shared__ float lA[256];
  int i = blockIdx.x, f = threadIdx.x;
  float s = 0.f;
  for (int jb = 0; jb < NROW; jb += 256) {
    __syncthreads();
    lA[threadIdx.x] = A[(size_t)i * NROW + jb + threadIdx.x];
    __syncthreads();
    for (int jj = 0; jj < 256; ++jj) s += lA[jj] * Y[(size_t)(jb + jj) * OUTF + f];
  }
  out[(size_t)i * OUTF + f] = dv[i] * s;
}

extern "C" void kernel_launch(void* const* d_in, const int* in_sizes, int n_in,
                              void* d_out, int out_size, void* d_ws, size_t ws_size,
                              hipStream_t stream) {
  const float* A = (const float*)d_in[0];
  const float* X = (const float*)d_in[1];
  const float* W = (const float*)d_in[2];
  float* out = (float*)d_out;

  const size_t SZ_YT  = (size_t)OUTF * NROW * 2;       // 4 MiB
  const size_t SZ_WST = (size_t)OUTF * INF * 2;        // 256 KiB
  const size_t SZ_D   = (size_t)NROW * 4;              // 32 KiB
  const size_t SZ_P   = (size_t)8 * NROW * OUTF * 2;   // 32 MiB (bf16)
  const size_t SZ_ABF = (size_t)NROW * NROW * 2;       // 128 MiB (bf16 A)
  const size_t NEED_BASE = SZ_YT + SZ_WST + SZ_D + SZ_P;
  const size_t NEED_FULL = NEED_BASE + SZ_ABF;

  char* p = (char*)d_ws;
  if (ws_size >= NEED_FULL) {
    unsigned short* YT  = (unsigned short*)p; p += SZ_YT;
    unsigned short* WsT = (unsigned short*)p; p += SZ_WST;
    float* dv = (float*)p; p += SZ_D;
    unsigned short* P = (unsigned short*)p; p += SZ_P;
    unsigned short* Abf = (unsigned short*)p;

    k_rowsum_cvt_w<<<dim3(2048), dim3(256), 0, stream>>>(A, W, dv, Abf, WsT);
    k_support_fx64<<<dim3(2, 128), dim3(256), 0, stream>>>(WsT, X, dv, YT);
    k_gemm_main_bf16a<<<dim3(64, 8), dim3(256), 0, stream>>>(Abf, YT, P);
    k_reduce8<<<dim3(2048), dim3(256), 0, stream>>>((const ushort4*)P, dv, (float4*)out);
  } else if (ws_size >= NEED_BASE) {
    unsigned short* YT  = (unsigned short*)p; p += SZ_YT;
    unsigned short* WsT = (unsigned short*)p; p += SZ_WST;
    float* dv = (float*)p; p += SZ_D;
    unsigned short* P = (unsigned short*)p;

    k_convert_w<<<dim3(512), dim3(256), 0, stream>>>(W, WsT);
    k_rowsum<<<dim3(2048), dim3(256), 0, stream>>>(A, dv);
    k_support_fx<<<dim3(2, 64), dim3(256), 0, stream>>>(WsT, X, dv, YT);
    k_gemm_main_f32a<<<dim3(64, 8), dim3(256), 0, stream>>>(A, YT, P);
    k_reduce8<<<dim3(2048), dim3(256), 0, stream>>>((const ushort4*)P, dv, (float4*)out);
  } else {
    float* dv = (float*)p; p += SZ_D;
    float* Y  = (float*)p;
    k_rowsum<<<dim3(2048), dim3(256), 0, stream>>>(A, dv);
    k_support_naive<<<dim3(8192), dim3(256), 0, stream>>>(X, W, dv, Y);
    k_main_naive<<<dim3(8192), dim3(256), 0, stream>>>(A, Y, dv, out);
  }
}